// Round 9
// baseline (1076.237 us; speedup 1.0000x reference)
//
#include <hip/hip_runtime.h>
#include <hip/hip_fp16.h>

#define N_NODES 50000
#define N_EDGES 800000
#define F_INN   128
#define F_HID   96
#define F_OUTT  40
#define NTILES  ((N_NODES + 63) / 64)     // 782
#define NSCANB  ((N_NODES + 1023) / 1024) // 49

typedef _Float16 half8 __attribute__((ext_vector_type(8)));
typedef float    floatx4 __attribute__((ext_vector_type(4)));

// ---------------------------------------------------------------------------
// Grid barrier: device-scope sense barrier. bar[0]=count, bar[1]=generation.
// Requires all blocks co-resident (grid sized via occupancy query).
// ---------------------------------------------------------------------------
__device__ __forceinline__ void gbar(unsigned* bar, int G) {
    __syncthreads();
    if (threadIdx.x == 0) {
        __threadfence();   // agent-scope release of this block's prior writes
        unsigned g = __hip_atomic_load(bar + 1, __ATOMIC_RELAXED,
                                       __HIP_MEMORY_SCOPE_AGENT);
        unsigned a = __hip_atomic_fetch_add(bar, 1u, __ATOMIC_ACQ_REL,
                                            __HIP_MEMORY_SCOPE_AGENT);
        if (a == (unsigned)G - 1) {
            __hip_atomic_store(bar, 0u, __ATOMIC_RELAXED,
                               __HIP_MEMORY_SCOPE_AGENT);
            __hip_atomic_fetch_add(bar + 1, 1u, __ATOMIC_RELEASE,
                                   __HIP_MEMORY_SCOPE_AGENT);
        } else {
            while (__hip_atomic_load(bar + 1, __ATOMIC_ACQUIRE,
                                     __HIP_MEMORY_SCOPE_AGENT) == g)
                __builtin_amdgcn_s_sleep(2);
        }
    }
    __syncthreads();
}

// ---------------------------------------------------------------------------
// MFMA GEMM phase (round-6/8 proven body, grid-stride tiles).
// ---------------------------------------------------------------------------
template <int FI, typename TIN>
__device__ __forceinline__ void gemm_phase(
        const TIN* __restrict__ X, const __half* __restrict__ BTg,  // [96][136]
        float4* __restrict__ Th4, __half* BTl, __half* OUTl, int G) {
    int tid = threadIdx.x;
    {   // stage BT (1632 x 16B) once per phase
        const int4* s = reinterpret_cast<const int4*>(BTg);
        int4* d = reinterpret_cast<int4*>(BTl);
        for (int i = tid; i < 96 * 136 / 8; i += 256) d[i] = s[i];
    }
    __syncthreads();
    int lane = tid & 63, w = tid >> 6;
    int lm = lane & 15, q = lane >> 4;
    for (int bx = blockIdx.x; bx < NTILES; bx += G) {
        int base = bx * 64 + w * 16;
        int node = base + lm;
        int nclamp = min(node, N_NODES - 1);
        const TIN* Xrow = X + (size_t)nclamp * FI;

        floatx4 cf[6];
        #pragma unroll
        for (int t = 0; t < 6; ++t) cf[t] = (floatx4){0.f, 0.f, 0.f, 0.f};

        constexpr int KS = FI / 32;
        #pragma unroll
        for (int ks = 0; ks < KS; ++ks) {
            half8 bv;
            if constexpr (sizeof(TIN) == 4) {
                const float4* xr = reinterpret_cast<const float4*>(Xrow + 32 * ks + q * 8);
                float4 f0 = xr[0], f1 = xr[1];
                union { half8 v; __half2 h[4]; } b;
                b.h[0] = __floats2half2_rn(f0.x, f0.y);
                b.h[1] = __floats2half2_rn(f0.z, f0.w);
                b.h[2] = __floats2half2_rn(f1.x, f1.y);
                b.h[3] = __floats2half2_rn(f1.z, f1.w);
                bv = b.v;
            } else {
                bv = *reinterpret_cast<const half8*>(Xrow + 32 * ks + q * 8);
            }
            #pragma unroll
            for (int t = 0; t < 6; ++t) {
                half8 a = *reinterpret_cast<const half8*>(
                    &BTl[(t * 16 + lm) * 136 + q * 8 + 32 * ks]);
                cf[t] = __builtin_amdgcn_mfma_f32_16x16x32_f16(a, bv, cf[t], 0, 0, 0);
            }
        }
        // Epilogue: per-wave LDS transpose -> coalesced float4 stores.
        __half* orow = OUTl + (w * 16 + lm) * 104;
        #pragma unroll
        for (int t = 0; t < 6; ++t) {
            union { int2 i2; __half2 h[2]; } u;
            u.h[0] = __floats2half2_rn(cf[t][0], cf[t][1]);
            u.h[1] = __floats2half2_rn(cf[t][2], cf[t][3]);
            *reinterpret_cast<int2*>(&orow[t * 16 + q * 4]) = u.i2;
        }
        #pragma unroll
        for (int R = 0; R < 3; ++R) {
            int nl = lane >> 2, c = (lane & 3) + 4 * R;
            float4 v = *reinterpret_cast<const float4*>(&OUTl[(w * 16 + nl) * 104 + c * 8]);
            int gn = base + nl;
            if (gn < N_NODES) Th4[(size_t)gn * 12 + c] = v;
        }
    }
}

// ---------------------------------------------------------------------------
// Aggregation phase (round-6/8 proven body, grid-stride, no early return).
// ---------------------------------------------------------------------------
__device__ __forceinline__ void agg_phase(
        const __half2* __restrict__ T, const int* __restrict__ row_start,
        const int* __restrict__ csr_src, const float* __restrict__ dinv,
        const float* __restrict__ bias, __half2* __restrict__ H, int G) {
    int lane = threadIdx.x & 63;
    int wv = threadIdx.x >> 6;
    int fl = min(lane, 47);
    for (int nb = blockIdx.x; nb * 4 < N_NODES; nb += G) {
        int node = __builtin_amdgcn_readfirstlane(nb * 4 + wv);
        if (node >= N_NODES) continue;
        float dn = dinv[node];
        float2 self = __half22float2(T[(size_t)node * 48 + fl]);
        float accx = dn * self.x, accy = dn * self.y;
        int idx = row_start[node];
        int end = row_start[node + 1];
        for (; idx + 8 <= end; idx += 8) {
            int s[8];
            #pragma unroll
            for (int u = 0; u < 8; ++u) s[u] = csr_src[idx + u];
            float ws[8];
            #pragma unroll
            for (int u = 0; u < 8; ++u) ws[u] = dinv[s[u]];
            float2 f[8];
            #pragma unroll
            for (int u = 0; u < 8; ++u) f[u] = __half22float2(T[(size_t)s[u] * 48 + fl]);
            #pragma unroll
            for (int u = 0; u < 8; ++u) {
                accx = fmaf(ws[u], f[u].x, accx);
                accy = fmaf(ws[u], f[u].y, accy);
            }
        }
        for (; idx < end; ++idx) {
            int s = csr_src[idx];
            float w = dinv[s];
            float2 f = __half22float2(T[(size_t)s * 48 + fl]);
            accx = fmaf(w, f.x, accx);
            accy = fmaf(w, f.y, accy);
        }
        if (lane < 48) {
            float2 b = reinterpret_cast<const float2*>(bias)[lane];
            float ox = fmaxf(fmaf(dn, accx, b.x), 0.f);
            float oy = fmaxf(fmaf(dn, accy, b.y), 0.f);
            H[(size_t)node * 48 + lane] = __floats2half2_rn(ox, oy);
        }
    }
}

// ---------------------------------------------------------------------------
// The whole GCN in one persistent kernel. 8 grid barriers, 0 launch gaps.
// Edge (dst, rank) cached in registers from count -> fill (no rank array).
// ---------------------------------------------------------------------------
__global__ __launch_bounds__(256, 4) void persist_kernel(
        const float* __restrict__ x, const int* __restrict__ src,
        const int* __restrict__ dst,
        const float* __restrict__ W1, const float* __restrict__ b1,
        const float* __restrict__ W2, const float* __restrict__ b2,
        const float* __restrict__ Wout, const float* __restrict__ bout,
        float* __restrict__ out,
        int* counts4, int4* base4, int* row_start, float* dinv,
        int* blk_sums, int* csr_src, __half* BT1, __half* BT2,
        __half* Th, __half* Hh, unsigned* bar) {
    __shared__ __align__(16) char ldsbuf[39424];
    __half* BTl  = (__half*)ldsbuf;            // 26112 B
    __half* OUTl = (__half*)(ldsbuf + 26112);  // 13312 B
    int*    s_ws = (int*)ldsbuf;               // scan scratch (18 ints)
    float*  Wo   = (float*)ldsbuf;             // gemm_out weights (15360 B)

    const int tid = threadIdx.x;
    const int G = gridDim.x;
    const int gstride = G * 256;
    const int gtid = blockIdx.x * 256 + tid;

    // ---- phase 0: zero counts4 + transpose weights to fp16 [96][136] ----
    for (int i = gtid; i < N_NODES; i += gstride)
        ((int4*)counts4)[i] = make_int4(0, 0, 0, 0);
    for (int i = gtid; i < 96 * 128 + 96 * 96; i += gstride) {
        if (i < 96 * 128) {
            int j = i / 128, k = i - j * 128;
            BT1[j * 136 + k] = __float2half(W1[k * 96 + j]);
        } else {
            int t = i - 96 * 128;
            int j = t / 96, k = t - j * 96;
            BT2[j * 136 + k] = __float2half(W2[k * 96 + j]);
        }
    }
    gbar(bar, G);

    // ---- phase 1: count (dst+rank cached in regs), then gemm L1 ----
    int dstv[8], rankv[8];
    #pragma unroll
    for (int k = 0; k < 8; ++k) {
        int i = gtid + k * gstride;
        if (i < N_EDGES) {
            int dd = dst[i];
            dstv[k] = dd;
            rankv[k] = atomicAdd(&counts4[dd * 4 + (i & 3)], 1);
        }
    }
    gemm_phase<F_INN, float>(x, BT1, (float4*)Th, BTl, OUTl, G);
    gbar(bar, G);

    // ---- phase 2: scan_local (blocks 0..48; 256 thr x 4 nodes) ----
    if ((int)blockIdx.x < NSCANB) {
        int lane = tid & 63, wid = tid >> 6;
        int base = (int)blockIdx.x * 1024 + tid * 4;
        int d[4], pre[4], tot = 0;
        #pragma unroll
        for (int j = 0; j < 4; ++j) {
            int node = base + j, dd = 0;
            if (node < N_NODES) {
                int4 c = ((const int4*)counts4)[node];
                dd = c.x + c.y + c.z + c.w;
            }
            d[j] = dd; pre[j] = tot; tot += dd;
        }
        int val = tot;
        #pragma unroll
        for (int off = 1; off < 64; off <<= 1) {
            int u = __shfl_up(val, off, 64);
            if (lane >= off) val += u;
        }
        if (lane == 63) s_ws[wid] = val;
        __syncthreads();
        if (tid == 0) {
            int a = s_ws[0];
            #pragma unroll
            for (int j = 1; j < 4; ++j) { a += s_ws[j]; s_ws[j] = a; }
            blk_sums[blockIdx.x] = a;
        }
        __syncthreads();
        int excl = (wid ? s_ws[wid - 1] : 0) + (val - tot);
        #pragma unroll
        for (int j = 0; j < 4; ++j) {
            int node = base + j;
            if (node < N_NODES) {
                row_start[node] = excl + pre[j];           // local
                dinv[node] = rsqrtf((float)(d[j] + 1));    // +1 self loop
            }
        }
    }
    gbar(bar, G);

    // ---- phase 3: scan_apply (blocks 0..48) ----
    if ((int)blockIdx.x < NSCANB) {
        if (tid < 64) {
            int v = (tid < NSCANB) ? blk_sums[tid] : 0;
            int val = v;
            #pragma unroll
            for (int off = 1; off < 64; off <<= 1) {
                int u = __shfl_up(val, off, 64);
                if (tid >= off) val += u;
            }
            if (tid == (int)blockIdx.x) s_ws[16] = val - v;  // excl prefix
            if (tid == 63) s_ws[17] = val;                   // total == E
        }
        __syncthreads();
        int myoff = s_ws[16];
        int base = (int)blockIdx.x * 1024 + tid * 4;
        #pragma unroll
        for (int j = 0; j < 4; ++j) {
            int node = base + j;
            if (node < N_NODES) {
                int4 c = ((const int4*)counts4)[node];
                int b = row_start[node] + myoff;
                row_start[node] = b;
                base4[node] = make_int4(b, b + c.x, b + c.x + c.y,
                                        b + c.x + c.y + c.z);
            }
        }
        if (blockIdx.x == 0 && tid == 0) row_start[N_NODES] = s_ws[17];
    }
    gbar(bar, G);

    // ---- phase 4: fill (atomic-free; dst/rank from registers) ----
    #pragma unroll
    for (int k = 0; k < 8; ++k) {
        int i = gtid + k * gstride;
        if (i < N_EDGES) {
            const int* b4 = (const int*)base4;
            csr_src[b4[dstv[k] * 4 + (i & 3)] + rankv[k]] = src[i];
        }
    }
    gbar(bar, G);

    // ---- phase 5: aggregation L1 ----
    agg_phase((const __half2*)Th, row_start, csr_src, dinv, b1,
              (__half2*)Hh, G);
    gbar(bar, G);

    // ---- phase 6: gemm L2 (fp16 in) ----
    gemm_phase<F_HID, __half>(Hh, BT2, (float4*)Th, BTl, OUTl, G);
    gbar(bar, G);

    // ---- phase 7: aggregation L2 ----
    agg_phase((const __half2*)Th, row_start, csr_src, dinv, b2,
              (__half2*)Hh, G);
    gbar(bar, G);

    // ---- phase 8: output GEMM (25 nodes x 10 j-quads per block-tile) ----
    for (int i = tid; i < 96 * 40 / 4; i += 256)
        ((float4*)Wo)[i] = ((const float4*)Wout)[i];
    __syncthreads();
    {
        int jx = tid % 10, ny = tid / 10;   // ny 0..25
        for (int t = blockIdx.x; t < N_NODES / 25; t += G) {
            if (tid < 250) {
                int node = t * 25 + ny;
                int j = jx * 4;
                const __half2* Ah = (const __half2*)Hh + (size_t)node * 48;
                float4 acc = make_float4(0.f, 0.f, 0.f, 0.f);
                for (int k2 = 0; k2 < 48; k2 += 2) {
                    float2 a01 = __half22float2(Ah[k2]);
                    float2 a23 = __half22float2(Ah[k2 + 1]);
                    int k = 2 * k2;
                    float4 w0 = *(const float4*)(Wo + (k + 0) * 40 + j);
                    float4 w1 = *(const float4*)(Wo + (k + 1) * 40 + j);
                    float4 w2 = *(const float4*)(Wo + (k + 2) * 40 + j);
                    float4 w3 = *(const float4*)(Wo + (k + 3) * 40 + j);
                    acc.x += a01.x * w0.x + a01.y * w1.x + a23.x * w2.x + a23.y * w3.x;
                    acc.y += a01.x * w0.y + a01.y * w1.y + a23.x * w2.y + a23.y * w3.y;
                    acc.z += a01.x * w0.z + a01.y * w1.z + a23.x * w2.z + a23.y * w3.z;
                    acc.w += a01.x * w0.w + a01.y * w1.w + a23.x * w2.w + a23.y * w3.w;
                }
                float4 b = *(const float4*)(bout + j);
                acc.x += b.x; acc.y += b.y; acc.z += b.z; acc.w += b.w;
                *(float4*)(out + (size_t)node * 40 + j) = acc;
            }
        }
    }
}

// ---------------------------------------------------------------------------

extern "C" void kernel_launch(void* const* d_in, const int* in_sizes, int n_in,
                              void* d_out, int out_size, void* d_ws, size_t ws_size,
                              hipStream_t stream) {
    const float* x    = (const float*)d_in[0];
    const int*   ei   = (const int*)d_in[1];
    const float* W1   = (const float*)d_in[2];
    const float* b1   = (const float*)d_in[3];
    const float* W2   = (const float*)d_in[4];
    const float* b2   = (const float*)d_in[5];
    const float* Wout = (const float*)d_in[6];
    const float* bout = (const float*)d_in[7];
    float*       out  = (float*)d_out;

    const int* src = ei;            // edge_index[0]
    const int* dst = ei + N_EDGES;  // edge_index[1]

    char* ws = (char*)d_ws;
    size_t off = 0;
    auto alloc = [&](size_t bytes) {
        size_t o = off;
        off = (off + bytes + 511) & ~(size_t)511;
        return (void*)(ws + o);
    };
    int*      counts4   = (int*)     alloc((size_t)N_NODES * 4 * sizeof(int));
    int4*     base4     = (int4*)    alloc((size_t)N_NODES * sizeof(int4));
    int*      row_start = (int*)     alloc((N_NODES + 1) * sizeof(int));
    float*    dinv      = (float*)   alloc(N_NODES * sizeof(float));
    int*      blk_sums  = (int*)     alloc(64 * sizeof(int));
    int*      csr_src   = (int*)     alloc((size_t)N_EDGES * sizeof(int));
    __half*   BT1       = (__half*)  alloc((size_t)96 * 136 * sizeof(__half));
    __half*   BT2       = (__half*)  alloc((size_t)96 * 136 * sizeof(__half));
    __half*   Th        = (__half*)  alloc((size_t)N_NODES * 96 * sizeof(__half));
    __half*   Hh        = (__half*)  alloc((size_t)N_NODES * 96 * sizeof(__half));
    unsigned* bar       = (unsigned*)alloc(64);

    // Grid size: max co-resident blocks (occupancy-verified), clamped so the
    // register edge-cache (8 slots) always covers all edges (G >= 392) and
    // barrier cost stays bounded (G <= 1024 = 4 blocks/CU by 39.4 KB LDS).
    int nb = 0;
    (void)hipOccupancyMaxActiveBlocksPerMultiprocessor(&nb, persist_kernel, 256, 0);
    int G = nb * 256;
    if (G < 392)  G = 392;
    if (G > 1024) G = 1024;

    hipMemsetAsync(bar, 0, 64, stream);   // barrier count + generation
    persist_kernel<<<G, 256, 0, stream>>>(
        x, src, dst, W1, b1, W2, b2, Wout, bout, out,
        counts4, base4, row_start, dinv, blk_sums, csr_src,
        BT1, BT2, Th, Hh, bar);
}

// Round 10
// 243.698 us; speedup vs baseline: 4.4163x; 4.4163x over previous
//
#include <hip/hip_runtime.h>
#include <hip/hip_fp16.h>

#define N_NODES 50000
#define N_EDGES 800000
#define F_INN   128
#define F_HID   96
#define F_OUTT  40

typedef _Float16 half8 __attribute__((ext_vector_type(8)));
typedef float    floatx4 __attribute__((ext_vector_type(4)));

// ---------------------------------------------------------------------------
// MFMA GEMM body (round-6 proven): T[n][96] (fp16) = X[n x FI] @ W.
// A = W^T tile from LDS (staged once per block, 64x reuse), B = node rows.
// Epilogue transposes through per-wave LDS -> coalesced float4 stores.
// 4 waves x 16 nodes = 64 nodes/block.
// ---------------------------------------------------------------------------
template <int FI, typename TIN>
__device__ __forceinline__ void mfma_gemm_body(
        const TIN* __restrict__ X, const __half* __restrict__ BTg,  // [96][136]
        float4* __restrict__ Th4, int n, int bx) {
    __shared__ __half BTl[96 * 136];          // 26112 B
    __shared__ __half OUTl[4 * 16 * 104];     // 13312 B
    int tid = threadIdx.x;
    {   // stage BT (1632 x 16B)
        const int4* s = reinterpret_cast<const int4*>(BTg);
        int4* d = reinterpret_cast<int4*>(BTl);
        for (int i = tid; i < 96 * 136 / 8; i += 256) d[i] = s[i];
    }
    __syncthreads();

    int lane = tid & 63, w = tid >> 6;
    int lm = lane & 15, q = lane >> 4;
    int base = bx * 64 + w * 16;
    int node = base + lm;
    int nclamp = min(node, n - 1);
    const TIN* Xrow = X + (size_t)nclamp * FI;

    floatx4 cf[6];
    #pragma unroll
    for (int t = 0; t < 6; ++t) cf[t] = (floatx4){0.f, 0.f, 0.f, 0.f};

    constexpr int KS = FI / 32;
    #pragma unroll
    for (int ks = 0; ks < KS; ++ks) {
        half8 bv;
        if constexpr (sizeof(TIN) == 4) {
            const float4* xr = reinterpret_cast<const float4*>(Xrow + 32 * ks + q * 8);
            float4 f0 = xr[0], f1 = xr[1];
            union { half8 v; __half2 h[4]; } b;
            b.h[0] = __floats2half2_rn(f0.x, f0.y);
            b.h[1] = __floats2half2_rn(f0.z, f0.w);
            b.h[2] = __floats2half2_rn(f1.x, f1.y);
            b.h[3] = __floats2half2_rn(f1.z, f1.w);
            bv = b.v;
        } else {
            bv = *reinterpret_cast<const half8*>(Xrow + 32 * ks + q * 8);
        }
        #pragma unroll
        for (int t = 0; t < 6; ++t) {
            half8 a = *reinterpret_cast<const half8*>(
                &BTl[(t * 16 + lm) * 136 + q * 8 + 32 * ks]);
            cf[t] = __builtin_amdgcn_mfma_f32_16x16x32_f16(a, bv, cf[t], 0, 0, 0);
        }
    }

    // Epilogue: D[row=q*4+r][col=lm] = out[feature = t*16+q*4+r][node=lm].
    __half* orow = OUTl + (w * 16 + lm) * 104;
    #pragma unroll
    for (int t = 0; t < 6; ++t) {
        union { int2 i2; __half2 h[2]; } u;
        u.h[0] = __floats2half2_rn(cf[t][0], cf[t][1]);
        u.h[1] = __floats2half2_rn(cf[t][2], cf[t][3]);
        *reinterpret_cast<int2*>(&orow[t * 16 + q * 4]) = u.i2;
    }
    #pragma unroll
    for (int R = 0; R < 3; ++R) {
        int nl = lane >> 2, c = (lane & 3) + 4 * R;
        float4 v = *reinterpret_cast<const float4*>(&OUTl[(w * 16 + nl) * 104 + c * 8]);
        int gn = base + nl;
        if (gn < n) Th4[(size_t)gn * 12 + c] = v;
    }
}

// ---------------------------------------------------------------------------
// Fused: count (blocks [0,nCB)) + gemm L1 (blocks [nCB, nCB+GB)) — independent.
// (Round-6 proven: one launch covering both beats two launches + gap.)
// ---------------------------------------------------------------------------
__global__ __launch_bounds__(256) void count_gemm1_kernel(
        const int* __restrict__ dst, int* __restrict__ counts4, int* __restrict__ rank,
        int e, const float* __restrict__ X, const __half* __restrict__ BT1,
        float4* __restrict__ Th4, int n, int nCB) {
    if ((int)blockIdx.x < nCB) {
        int i = blockIdx.x * 256 + threadIdx.x;
        if (i < e) rank[i] = atomicAdd(&counts4[dst[i] * 4 + (i & 3)], 1);
    } else {
        mfma_gemm_body<F_INN, float>(X, BT1, Th4, n, blockIdx.x - nCB);
    }
}

template <int FI, typename TIN>
__global__ __launch_bounds__(256) void mfma_gemm_kernel(
        const TIN* __restrict__ X, const __half* __restrict__ BTg,
        float4* __restrict__ Th4, int n) {
    mfma_gemm_body<FI, TIN>(X, BTg, Th4, n, blockIdx.x);
}

// ---------------------------------------------------------------------------
// Weight transpose + fp16: W[K x 96] -> BT[96][136] (pad 8). W1 & W2 together.
// ---------------------------------------------------------------------------
__global__ void wt_kernel(const float* __restrict__ W1, const float* __restrict__ W2,
                          __half* __restrict__ BT1, __half* __restrict__ BT2) {
    int i = blockIdx.x * 256 + threadIdx.x;
    if (i < 96 * 128) {
        int j = i / 128, k = i - j * 128;
        BT1[j * 136 + k] = __float2half(W1[k * 96 + j]);
    } else if (i < 96 * 128 + 96 * 96) {
        int t = i - 96 * 128;
        int j = t / 96, k = t - j * 96;
        BT2[j * 136 + k] = __float2half(W2[k * 96 + j]);
    }
}

// ---------------------------------------------------------------------------
// Scan phase 1: per-block exclusive scan of node degrees; dinv; block sums.
// ---------------------------------------------------------------------------
__global__ __launch_bounds__(1024) void scan_local_kernel(
        const int4* __restrict__ counts4, int* __restrict__ row_start,
        float* __restrict__ dinv, int* __restrict__ blk_sums, int n) {
    __shared__ int wave_sums[16];
    int tid = threadIdx.x, lane = tid & 63, wid = tid >> 6;
    int i = blockIdx.x * 1024 + tid;
    int v = 0;
    if (i < n) {
        int4 c = counts4[i];
        v = c.x + c.y + c.z + c.w;
    }
    int val = v;
    #pragma unroll
    for (int off = 1; off < 64; off <<= 1) {
        int u = __shfl_up(val, off, 64);
        if (lane >= off) val += u;
    }
    if (lane == 63) wave_sums[wid] = val;
    __syncthreads();
    if (wid == 0) {
        int w = (lane < 16) ? wave_sums[lane] : 0;
        #pragma unroll
        for (int off = 1; off < 16; off <<= 1) {
            int u = __shfl_up(w, off, 64);
            if (lane >= off) w += u;
        }
        if (lane < 16) wave_sums[lane] = w;
    }
    __syncthreads();
    int excl = ((wid == 0) ? 0 : wave_sums[wid - 1]) + (val - v);
    if (i < n) {
        row_start[i] = excl;                  // local; global offset in phase 2
        dinv[i] = rsqrtf((float)(v + 1));     // +1 self loop
    }
    if (tid == 0) blk_sums[blockIdx.x] = wave_sums[15];
}

// ---------------------------------------------------------------------------
// Scan phase 2+3 fused: every block redundantly scans the <=64 block sums,
// applies its own offset, emits per-shard bases base4. Block 0 writes total.
// ---------------------------------------------------------------------------
__global__ __launch_bounds__(1024) void scan_apply_kernel(
        int* __restrict__ row_start, const int* __restrict__ blk_sums,
        const int4* __restrict__ counts4, int4* __restrict__ base4, int n, int nblk) {
    __shared__ int s_my, s_tot;
    int tid = threadIdx.x;
    if (tid < 64) {
        int v = (tid < nblk) ? blk_sums[tid] : 0;
        int val = v;
        #pragma unroll
        for (int off = 1; off < 64; off <<= 1) {
            int u = __shfl_up(val, off, 64);
            if (tid >= off) val += u;
        }
        if (tid == (int)blockIdx.x) s_my = val - v;   // exclusive prefix
        if (tid == 63) s_tot = val;                   // grand total == E
    }
    __syncthreads();
    int i = blockIdx.x * 1024 + tid;
    if (i < n) {
        int4 c = counts4[i];
        int b = row_start[i] + s_my;
        row_start[i] = b;
        base4[i] = make_int4(b, b + c.x, b + c.x + c.y, b + c.x + c.y + c.z);
    }
    if (blockIdx.x == 0 && tid == 0) row_start[n] = s_tot;
}

// Atomic-free fill: pos = base4[dst].shard + rank.  One scattered 4B store.
__global__ void fill_csr_kernel(const int* __restrict__ src, const int* __restrict__ dst,
                                const int* __restrict__ rank, const int* __restrict__ base4,
                                int* __restrict__ csr_src, int e) {
    int i = blockIdx.x * blockDim.x + threadIdx.x;
    if (i >= e) return;
    csr_src[base4[dst[i] * 4 + (i & 3)] + rank[i]] = src[i];
}

// ---------------------------------------------------------------------------
// Aggregation L1 (round-6 proven): one wave per node; wave-uniform scalar
// dinv[s].  H[d] = relu(dinv[d]*(Σ dinv[s]T[s] + dinv[d]T[d]) + b), fp16 out.
// ---------------------------------------------------------------------------
__global__ __launch_bounds__(256) void agg_kernel(
        const __half2* __restrict__ T, const int* __restrict__ row_start,
        const int* __restrict__ csr_src, const float* __restrict__ dinv,
        const float* __restrict__ bias, __half2* __restrict__ H, int n) {
    int lane = threadIdx.x & 63;
    int node = __builtin_amdgcn_readfirstlane(blockIdx.x * 4 + (threadIdx.x >> 6));
    if (node >= n) return;
    int fl = min(lane, 47);                    // lanes 48..63 duplicate lane 47

    float dn = dinv[node];
    float2 self = __half22float2(T[(size_t)node * 48 + fl]);
    float accx = dn * self.x, accy = dn * self.y;   // dinv[d]*T[d]

    int idx = row_start[node];
    int end = row_start[node + 1];
    for (; idx + 8 <= end; idx += 8) {
        int s[8];
        #pragma unroll
        for (int u = 0; u < 8; ++u) s[u] = csr_src[idx + u];
        float ws[8];
        #pragma unroll
        for (int u = 0; u < 8; ++u) ws[u] = dinv[s[u]];          // scalar loads
        float2 f[8];
        #pragma unroll
        for (int u = 0; u < 8; ++u) f[u] = __half22float2(T[(size_t)s[u] * 48 + fl]);
        #pragma unroll
        for (int u = 0; u < 8; ++u) {
            accx = fmaf(ws[u], f[u].x, accx);
            accy = fmaf(ws[u], f[u].y, accy);
        }
    }
    for (; idx < end; ++idx) {
        int s = csr_src[idx];
        float w = dinv[s];
        float2 f = __half22float2(T[(size_t)s * 48 + fl]);
        accx = fmaf(w, f.x, accx);
        accy = fmaf(w, f.y, accy);
    }
    if (lane < 48) {
        float2 b = reinterpret_cast<const float2*>(bias)[lane];
        float ox = fmaxf(fmaf(dn, accx, b.x), 0.f);
        float oy = fmaxf(fmaf(dn, accy, b.y), 0.f);
        H[(size_t)node * 48 + lane] = __floats2half2_rn(ox, oy);
    }
}

// ---------------------------------------------------------------------------
// Aggregation L2 + output GEMM, fused: same gather loop, but instead of
// storing H the wave keeps h (fp32) and computes out[node][0..39] directly.
// h round-trips through a wave-private LDS slab (no barrier needed); Wout
// rows are coalesced 160B loads, L1-resident after the first block.
// ---------------------------------------------------------------------------
__global__ __launch_bounds__(256) void agg_out_kernel(
        const __half2* __restrict__ T, const int* __restrict__ row_start,
        const int* __restrict__ csr_src, const float* __restrict__ dinv,
        const float* __restrict__ bias,              // b2
        const float* __restrict__ Wout, const float* __restrict__ bout,
        float* __restrict__ out, int n) {
    __shared__ float hbuf[4][96];                    // 1536 B, wave-private rows
    int lane = threadIdx.x & 63;
    int w    = threadIdx.x >> 6;
    int node = __builtin_amdgcn_readfirstlane(blockIdx.x * 4 + w);
    if (node >= n) return;
    int fl = min(lane, 47);

    float dn = dinv[node];
    float2 self = __half22float2(T[(size_t)node * 48 + fl]);
    float accx = dn * self.x, accy = dn * self.y;

    int idx = row_start[node];
    int end = row_start[node + 1];
    for (; idx + 8 <= end; idx += 8) {
        int s[8];
        #pragma unroll
        for (int u = 0; u < 8; ++u) s[u] = csr_src[idx + u];
        float ws[8];
        #pragma unroll
        for (int u = 0; u < 8; ++u) ws[u] = dinv[s[u]];
        float2 f[8];
        #pragma unroll
        for (int u = 0; u < 8; ++u) f[u] = __half22float2(T[(size_t)s[u] * 48 + fl]);
        #pragma unroll
        for (int u = 0; u < 8; ++u) {
            accx = fmaf(ws[u], f[u].x, accx);
            accy = fmaf(ws[u], f[u].y, accy);
        }
    }
    for (; idx < end; ++idx) {
        int s = csr_src[idx];
        float wv = dinv[s];
        float2 f = __half22float2(T[(size_t)s * 48 + fl]);
        accx = fmaf(wv, f.x, accx);
        accy = fmaf(wv, f.y, accy);
    }

    // h = relu(dn*acc + b2)  (fp32, never rounded to fp16) -> wave-private LDS
    if (lane < 48) {
        float2 b = reinterpret_cast<const float2*>(bias)[lane];
        hbuf[w][2 * lane]     = fmaxf(fmaf(dn, accx, b.x), 0.f);
        hbuf[w][2 * lane + 1] = fmaxf(fmaf(dn, accy, b.y), 0.f);
    }
    // wave-local LDS visibility: compiler inserts lgkmcnt wait; no barrier.

    // out[node][j] = sum_k h[k] * Wout[k][j] + bout[j], lanes 0..39
    if (lane < 40) {
        float acc = bout[lane];
        #pragma unroll 8
        for (int k = 0; k < 96; ++k)
            acc = fmaf(hbuf[w][k], Wout[k * 40 + lane], acc);   // h: LDS broadcast
        out[(size_t)node * 40 + lane] = acc;
    }
}

// ---------------------------------------------------------------------------

extern "C" void kernel_launch(void* const* d_in, const int* in_sizes, int n_in,
                              void* d_out, int out_size, void* d_ws, size_t ws_size,
                              hipStream_t stream) {
    const float* x    = (const float*)d_in[0];
    const int*   ei   = (const int*)d_in[1];
    const float* W1   = (const float*)d_in[2];
    const float* b1   = (const float*)d_in[3];
    const float* W2   = (const float*)d_in[4];
    const float* b2   = (const float*)d_in[5];
    const float* Wout = (const float*)d_in[6];
    const float* bout = (const float*)d_in[7];
    float*       out  = (float*)d_out;

    const int* src = ei;            // edge_index[0]
    const int* dst = ei + N_EDGES;  // edge_index[1]

    char* ws = (char*)d_ws;
    size_t off = 0;
    auto alloc = [&](size_t bytes) {
        size_t o = off;
        off = (off + bytes + 511) & ~(size_t)511;
        return (void*)(ws + o);
    };
    int*     counts4   = (int*)    alloc((size_t)N_NODES * 4 * sizeof(int));
    int4*    base4     = (int4*)   alloc((size_t)N_NODES * sizeof(int4));
    int*     row_start = (int*)    alloc((N_NODES + 1) * sizeof(int));
    float*   dinv      = (float*)  alloc(N_NODES * sizeof(float));
    int*     blk_sums  = (int*)    alloc(64 * sizeof(int));
    int*     rank      = (int*)    alloc((size_t)N_EDGES * sizeof(int));
    int*     csr_src   = (int*)    alloc((size_t)N_EDGES * sizeof(int));
    __half*  BT1       = (__half*) alloc((size_t)96 * 136 * sizeof(__half));
    __half*  BT2       = (__half*) alloc((size_t)96 * 136 * sizeof(__half));
    __half*  Th        = (__half*) alloc((size_t)N_NODES * 96 * sizeof(__half));
    __half*  Hh        = (__half*) alloc((size_t)N_NODES * 96 * sizeof(__half));

    const int NSCAN = (N_NODES + 1023) / 1024;   // 49
    const int CB    = (N_EDGES + 255) / 256;     // 3125
    const int GB    = (N_NODES + 63) / 64;       // 782

    // --- prep ---
    hipMemsetAsync(counts4, 0, (size_t)N_NODES * 4 * sizeof(int), stream);
    wt_kernel<<<(96 * 128 + 96 * 96 + 255) / 256, 256, 0, stream>>>(W1, W2, BT1, BT2);

    // --- fused: edge counting + layer-1 GEMM (independent; round-6 proven) ---
    count_gemm1_kernel<<<CB + GB, 256, 0, stream>>>(
        dst, counts4, rank, N_EDGES, x, BT1, (float4*)Th, N_NODES, CB);

    // --- scan x2 + fill ---
    scan_local_kernel<<<NSCAN, 1024, 0, stream>>>(
        (const int4*)counts4, row_start, dinv, blk_sums, N_NODES);
    scan_apply_kernel<<<NSCAN, 1024, 0, stream>>>(
        row_start, blk_sums, (const int4*)counts4, base4, N_NODES, NSCAN);
    fill_csr_kernel<<<CB, 256, 0, stream>>>(
        src, dst, rank, (const int*)base4, csr_src, N_EDGES);

    // --- layer 1 aggregation -> H (fp16) ---
    agg_kernel<<<(N_NODES + 3) / 4, 256, 0, stream>>>(
        (const __half2*)Th, row_start, csr_src, dinv, b1, (__half2*)Hh, N_NODES);

    // --- layer 2 GEMM (fp16 in) ---
    mfma_gemm_kernel<F_HID, __half><<<GB, 256, 0, stream>>>(
        (const __half*)Hh, BT2, (float4*)Th, N_NODES);

    // --- layer 2 aggregation + output GEMM, fused ---
    agg_out_kernel<<<(N_NODES + 3) / 4, 256, 0, stream>>>(
        (const __half2*)Th, row_start, csr_src, dinv, b2, Wout, bout, out, N_NODES);
}